// Round 13
// baseline (115.112 us; speedup 1.0000x reference)
//
#include <hip/hip_runtime.h>
#include <stdint.h>

// Swin shifted-window attention, MI355X (gfx950) — round 13.
// r12 pipeline + global_load_lds prefetch. Diagnosis: r12's VGPR=128 proves
// two 96-reg Raw sets can't coexist -> compiler re-rolled the prefetch ->
// MLP stayed ~2 loads/wave. global_load_lds gives a deep vmcnt queue with
// ZERO VGPR cost: Q+K of the next wh prefetch as 16 x 1KB direct-to-LDS
// bursts into a wave-PRIVATE 16KB slot (no syncthreads — r11's mistake).
// LDS dest (uniform base + lane*16) is exactly the fragment read pattern
// (lane 16g+l16 reads back its own 16B) -> identity roundtrip, conflict-free
// (8cy/b128, throughput-bound). V double-buffered in regs (64 VGPR, now
// affordable). Manual s_waitcnt vmcnt(0) + sched_barrier(0) before readback
// (compiler cannot see the glds->ds_read dependence).

constexpr int WSZ  = 7;
constexpr int NTOK = 49;
constexpr int NH_  = 16;
constexpr int HD_  = 32;
constexpr int SP   = 56;
constexpr int CH   = 512;
constexpr float LOG2E = 1.4426950408889634f;

constexpr int SLOT_BYTES = 16384;                  // per-wave: Q 8KB + K 8KB
constexpr size_t LDS_BYTES = 4 * SLOT_BYTES;       // 64KB per 4-wave block

typedef float    f32x4 __attribute__((ext_vector_type(4)));
typedef short    s16x8 __attribute__((ext_vector_type(8)));
typedef _Float16 f16x4 __attribute__((ext_vector_type(4)));

union FragU { uint32_t w[4]; s16x8 v; };

__device__ __forceinline__ uint32_t bf16_hibits(float x) {
    uint32_t u = __float_as_uint(x);
    u += 0x7fffu + ((u >> 16) & 1u);
    return u & 0xffff0000u;
}
__device__ __forceinline__ uint32_t pk_bf16(float a, float b) {
    return (bf16_hibits(a) >> 16) | bf16_hibits(b);
}

// async global->LDS, 16B per lane, dest = uniform base + lane*16
__device__ __forceinline__ void glds16(const float* g, void* l) {
    __builtin_amdgcn_global_load_lds(
        (const __attribute__((address_space(1))) uint32_t*)g,
        (__attribute__((address_space(3))) uint32_t*)l,
        16, 0, 0);
}

// ---------------- pre-kernel: bias+mask matrices (f16) ----------------
// bm[h*4+cls][q][m] (64x64 f16) = (bias+mask)*LOG2E; padding = -1000.
__global__ __launch_bounds__(256)
void build_bm(const float* __restrict__ bias, _Float16* __restrict__ bm)
{
    const int blk = blockIdx.x;          // h*4 + cls
    const int h = blk >> 2, cls = blk & 3;
    for (int idx = threadIdx.x; idx < 4096; idx += 256) {
        const int q = idx >> 6, m = idx & 63;
        float val;
        if (q >= NTOK || m >= NTOK) {
            val = -1000.0f;
        } else {
            const int iq = q / 7, jq = q % 7, im = m / 7, jm = m % 7;
            const int rpi = (iq - im + 6) * 13 + (jq - jm + 6);
            const float bv = bias[rpi * NH_ + h];
            const int rq = ((cls & 2) ? (iq < 4 ? 3 : 6) : 0)
                         + ((cls & 1) ? (jq < 4 ? 1 : 2) : 0);
            const int rm = ((cls & 2) ? (im < 4 ? 3 : 6) : 0)
                         + ((cls & 1) ? (jm < 4 ? 1 : 2) : 0);
            const float mask = (rq != rm) ? -100.0f : 0.0f;
            val = (bv + mask) * LOG2E;
        }
        bm[blk * 4096 + idx] = (_Float16)val;
    }
}

// ---------------- pipeline building blocks ----------------
struct Frag {
    s16x8 Qh[4], Kh[4], Vb[2][2];
};

__device__ __forceinline__ int make_off(int wh, int lane) {
    const int h  = wh & 15;
    const int w  = wh >> 4;
    const int wc = w & 7, wr = (w >> 3) & 7, b = w >> 6;
    const int t  = lane < NTOK ? lane : NTOK - 1;
    const int it = t / 7, jt = t - 7 * it;
    int sr = wr * 7 + it + 3; if (sr >= SP) sr -= SP;
    int sc = wc * 7 + jt + 3; if (sc >= SP) sc -= SP;
    return ((b * SP + sr) * SP + sc) * CH + h * HD_;
}
__device__ __forceinline__ int cls_of(int wh) {
    const int w = wh >> 4;
    return ((((w >> 3) & 7) == 7) ? 2 : 0) | (((w & 7) == 7) ? 1 : 0);
}

// prefetch Q,K rows of one wh into the wave-private LDS slot (no VGPR cost)
__device__ __forceinline__ void issue_glds(const float* __restrict__ qg,
                                           const float* __restrict__ kg,
                                           int off, int l16, int g, char* slot) {
#pragma unroll
    for (int tt = 0; tt < 4; ++tt) {
        const int o = __shfl(off, 16 * tt + l16);
        const float* qp = qg + o + 8 * g;
        const float* kp = kg + o + 8 * g;
        glds16(qp,     slot + (tt * 2 + 0) * 1024);
        glds16(qp + 4, slot + (tt * 2 + 1) * 1024);
        glds16(kp,     slot + 8192 + (tt * 2 + 0) * 1024);
        glds16(kp + 4, slot + 8192 + (tt * 2 + 1) * 1024);
    }
}

// V loads direct to registers (B-fragment gather pattern, r12-validated)
__device__ __forceinline__ void issue_v(const float* __restrict__ vg,
                                        int off, int l16, int g,
                                        float (&v)[2][2][8]) {
    int oV[16];
#pragma unroll
    for (int mc = 0; mc < 2; ++mc)
#pragma unroll
        for (int e = 0; e < 8; ++e)
            oV[8 * mc + e] = __shfl(off, 32 * mc + 8 * g + e);
#pragma unroll
    for (int mc = 0; mc < 2; ++mc)
#pragma unroll
        for (int dh = 0; dh < 2; ++dh)
#pragma unroll
            for (int e = 0; e < 8; ++e)
                v[mc][dh][e] = vg[oV[8 * mc + e] + 16 * dh + l16];
}

// LDS readback (identity mapping: lane reads its own 16B slots) + convert
__device__ __forceinline__ void readback_convert(const char* slot,
                                                 const float (&v)[2][2][8],
                                                 float qs, int lane, Frag& f) {
#pragma unroll
    for (int tt = 0; tt < 4; ++tt) {
        const float4 q0 = *(const float4*)(slot + (tt * 2 + 0) * 1024 + lane * 16);
        const float4 q1 = *(const float4*)(slot + (tt * 2 + 1) * 1024 + lane * 16);
        const float4 k0 = *(const float4*)(slot + 8192 + (tt * 2 + 0) * 1024 + lane * 16);
        const float4 k1 = *(const float4*)(slot + 8192 + (tt * 2 + 1) * 1024 + lane * 16);
        FragU qh, kh;
        qh.w[0] = pk_bf16(q0.x * qs, q0.y * qs);
        qh.w[1] = pk_bf16(q0.z * qs, q0.w * qs);
        qh.w[2] = pk_bf16(q1.x * qs, q1.y * qs);
        qh.w[3] = pk_bf16(q1.z * qs, q1.w * qs);
        kh.w[0] = pk_bf16(k0.x, k0.y);
        kh.w[1] = pk_bf16(k0.z, k0.w);
        kh.w[2] = pk_bf16(k1.x, k1.y);
        kh.w[3] = pk_bf16(k1.z, k1.w);
        f.Qh[tt] = qh.v; f.Kh[tt] = kh.v;
    }
#pragma unroll
    for (int mc = 0; mc < 2; ++mc)
#pragma unroll
        for (int dh = 0; dh < 2; ++dh) {
            FragU fu;
#pragma unroll
            for (int wd = 0; wd < 4; ++wd)
                fu.w[wd] = pk_bf16(v[mc][dh][2 * wd], v[mc][dh][2 * wd + 1]);
            f.Vb[mc][dh] = fu.v;
        }
}

__device__ __forceinline__ void load_bm(const _Float16* __restrict__ bmh,
                                        int l16, int g, f16x4 (&bmr)[4][4]) {
#pragma unroll
    for (int tq = 0; tq < 4; ++tq)
#pragma unroll
        for (int tk = 0; tk < 4; ++tk)
            bmr[tq][tk] = *(const f16x4*)(bmh + (16 * tq + l16) * 64 + 16 * tk + 4 * g);
}

__device__ __forceinline__ void do_math(const Frag& f, const f16x4 (&bmr)[4][4],
                                        int off, int lane, int g, int l16,
                                        float* __restrict__ outg) {
    // S^T = K·Q^T tiles, fused exp2 + bf16 pack + denom
    uint32_t u0[4][4], u1[4][4];
    float inv[4];
#pragma unroll
    for (int tq = 0; tq < 4; ++tq) {
        float dsum = 0.f;
#pragma unroll
        for (int tk = 0; tk < 4; ++tk) {
            f32x4 a;
            a[0] = (float)bmr[tq][tk][0] - 23.f;
            a[1] = (float)bmr[tq][tk][1] - 23.f;
            a[2] = (float)bmr[tq][tk][2] - 23.f;
            a[3] = (float)bmr[tq][tk][3] - 23.f;
            a = __builtin_amdgcn_mfma_f32_16x16x32_bf16(f.Kh[tk], f.Qh[tq], a, 0, 0, 0);
            float e0 = __builtin_amdgcn_exp2f(a[0]);
            float e1 = __builtin_amdgcn_exp2f(a[1]);
            float e2 = __builtin_amdgcn_exp2f(a[2]);
            float e3 = __builtin_amdgcn_exp2f(a[3]);
            dsum += (e0 + e1) + (e2 + e3);
            u0[tq][tk] = pk_bf16(e0, e1);
            u1[tq][tk] = pk_bf16(e2, e3);
        }
        dsum += __shfl_xor(dsum, 16);
        dsum += __shfl_xor(dsum, 32);
        inv[tq] = 1.0f / (dsum + 1e-30f);
    }

    // repack P (C-layout) -> A-fragments (r10-validated mapping)
    const int srcb = 32 * (g & 1) + l16;
    const bool hiG = (lane >= 32);
    s16x8 PA[4][2];
#pragma unroll
    for (int tq = 0; tq < 4; ++tq)
#pragma unroll
        for (int mc = 0; mc < 2; ++mc) {
            FragU fu;
#pragma unroll
            for (int wd = 0; wd < 4; ++wd) {
                const int sl = srcb + 16 * (wd >> 1);
                uint32_t A, B;
                if (wd & 1) {
                    A = __shfl(u1[tq][2 * mc],     sl);
                    B = __shfl(u1[tq][2 * mc + 1], sl);
                } else {
                    A = __shfl(u0[tq][2 * mc],     sl);
                    B = __shfl(u0[tq][2 * mc + 1], sl);
                }
                fu.w[wd] = hiG ? B : A;
            }
            PA[tq][mc] = fu.v;
        }

    // O = P·V, normalize + store; row q = 16tq+4g+r, col d = 16dh+l16
#pragma unroll
    for (int tq = 0; tq < 4; ++tq) {
        f32x4 acc[2];
#pragma unroll
        for (int dh = 0; dh < 2; ++dh) {
            f32x4 a = {0.f, 0.f, 0.f, 0.f};
            a = __builtin_amdgcn_mfma_f32_16x16x32_bf16(PA[tq][0], f.Vb[0][dh], a, 0, 0, 0);
            a = __builtin_amdgcn_mfma_f32_16x16x32_bf16(PA[tq][1], f.Vb[1][dh], a, 0, 0, 0);
            acc[dh] = a;
        }
#pragma unroll
        for (int r = 0; r < 4; ++r) {
            const float iv = __shfl(inv[tq], 4 * g + r);
            const int oo = __shfl(off, 16 * tq + 4 * g + r);
            if (tq < 3 || (g == 0 && r == 0)) {
#pragma unroll
                for (int dh = 0; dh < 2; ++dh)
                    outg[oo + 16 * dh + l16] = acc[dh][r] * iv;
            }
        }
    }
}

// wait for all outstanding VMEM (incl. global_load_lds) then fence scheduling
__device__ __forceinline__ void wait_vmem() {
    asm volatile("s_waitcnt vmcnt(0)" ::: "memory");
    __builtin_amdgcn_sched_barrier(0);
}

// ---------------- main glds-pipelined kernel ----------------
__global__ __launch_bounds__(256, 2)
void swin_glds_kernel(const float* __restrict__ qg,
                      const float* __restrict__ kg,
                      const float* __restrict__ vg,
                      const _Float16* __restrict__ bm,
                      float* __restrict__ outg)
{
    extern __shared__ char smem[];
    const int wave = threadIdx.x >> 6;
    char* slot = smem + wave * SLOT_BYTES;      // wave-private: no syncthreads
    const int gw   = blockIdx.x * 4 + wave;     // 0..4095; wh_i = gw + 4096*i
    const int lane = threadIdx.x & 63;
    const int g    = lane >> 4;
    const int l16  = lane & 15;
    const float qs = 0.17677669529663687f * LOG2E;

    const int h = gw & 15;
    const _Float16* bmhead = bm + (size_t)h * 4 * 4096;

    float VA[2][2][8], VB[2][2][8];
    Frag f;
    f16x4 bmr[4][4];

    const int wh0 = gw;
    const int off0 = make_off(wh0, lane);
    issue_glds(qg, kg, off0, l16, g, slot);
    issue_v(vg, off0, l16, g, VA);

    // ---- iteration 0: consume VA/slot(wh0), prefetch wh1 -> slot,VB ----
    wait_vmem();
    readback_convert(slot, VA, qs, lane, f);
    load_bm(bmhead + cls_of(wh0) * 4096, l16, g, bmr);
    __builtin_amdgcn_sched_barrier(0);
    const int wh1 = gw + 4096;
    const int off1 = make_off(wh1, lane);
    issue_glds(qg, kg, off1, l16, g, slot);
    issue_v(vg, off1, l16, g, VB);
    __builtin_amdgcn_sched_barrier(0);
    do_math(f, bmr, off0, lane, g, l16, outg);

    // ---- iteration 1: consume VB/slot(wh1), prefetch wh2 -> slot,VA ----
    wait_vmem();
    readback_convert(slot, VB, qs, lane, f);
    load_bm(bmhead + cls_of(wh1) * 4096, l16, g, bmr);
    __builtin_amdgcn_sched_barrier(0);
    const int wh2 = gw + 8192;
    const int off2 = make_off(wh2, lane);
    issue_glds(qg, kg, off2, l16, g, slot);
    issue_v(vg, off2, l16, g, VA);
    __builtin_amdgcn_sched_barrier(0);
    do_math(f, bmr, off1, lane, g, l16, outg);

    // ---- iteration 2: consume VA/slot(wh2), prefetch wh3 -> slot,VB ----
    wait_vmem();
    readback_convert(slot, VA, qs, lane, f);
    load_bm(bmhead + cls_of(wh2) * 4096, l16, g, bmr);
    __builtin_amdgcn_sched_barrier(0);
    const int wh3 = gw + 12288;
    const int off3 = make_off(wh3, lane);
    issue_glds(qg, kg, off3, l16, g, slot);
    issue_v(vg, off3, l16, g, VB);
    __builtin_amdgcn_sched_barrier(0);
    do_math(f, bmr, off2, lane, g, l16, outg);

    // ---- iteration 3: consume VB/slot(wh3), no prefetch ----
    wait_vmem();
    readback_convert(slot, VB, qs, lane, f);
    load_bm(bmhead + cls_of(wh3) * 4096, l16, g, bmr);
    __builtin_amdgcn_sched_barrier(0);
    do_math(f, bmr, off3, lane, g, l16, outg);
}

// ---------------- fallback scalar kernel (round-3) ----------------
__global__ __launch_bounds__(256)
void swin_block_scalar(const float* __restrict__ qg,
                       const float* __restrict__ kg,
                       const float* __restrict__ vg,
                       const float* __restrict__ bias,
                       float* __restrict__ outg)
{
    const int wave = __builtin_amdgcn_readfirstlane(threadIdx.x >> 6);
    const int wh   = blockIdx.x * 4 + wave;
    const int h    = wh & (NH_ - 1);
    const int w    = wh >> 4;
    const int wc   = w & 7;
    const int wr   = (w >> 3) & 7;
    const int b    = w >> 6;

    const int lane = threadIdx.x & 63;
    const int rr   = lane < NTOK ? lane : NTOK - 1;
    const int i    = rr / WSZ;
    const int j    = rr - i * WSZ;

    const int hp = wr * WSZ + i;
    const int wp = wc * WSZ + j;
    int sr = hp + 3; if (sr >= SP) sr -= SP;
    int sc = wp + 3; if (sc >= SP) sc -= SP;
    const int rowoff = ((b * SP + sr) * SP + sc) * CH + h * HD_;
    const int reg_r = (hp < 49 ? 0 : (hp < 53 ? 3 : 6))
                    + (wp < 49 ? 0 : (wp < 53 ? 1 : 2));
    const float qscale = 0.17677669529663687f * LOG2E;

    float qr[HD_];
    {
        const float4* qp = reinterpret_cast<const float4*>(qg + rowoff);
#pragma unroll
        for (int tt = 0; tt < HD_ / 4; ++tt) {
            float4 x = qp[tt];
            qr[4*tt+0] = x.x * qscale; qr[4*tt+1] = x.y * qscale;
            qr[4*tt+2] = x.z * qscale; qr[4*tt+3] = x.w * qscale;
        }
    }
    const int biaslane = (i * 13 + j) * 16 + h;
    float o[HD_];
#pragma unroll
    for (int d = 0; d < HD_; ++d) o[d] = 0.f;
    float denom = 0.f;
    const float* kb = kg + b * SP * SP * CH + h * HD_;
    const float* vb = vg + b * SP * SP * CH + h * HD_;

    for (int ic = 0; ic < WSZ; ++ic) {
        const int hpc = wr * WSZ + ic;
        int src_r = hpc + 3; if (src_r >= SP) src_r -= SP;
        const int regh_c = (hpc < 49 ? 0 : (hpc < 53 ? 3 : 6));
        const float* krow0 = kb + src_r * SP * CH;
        const float* vrow0 = vb + src_r * SP * CH;
        float e[WSZ];
#pragma unroll
        for (int u = 0; u < WSZ; ++u) {
            const int wpc = wc * WSZ + u;
            int src_c = wpc + 3; if (src_c >= SP) src_c -= SP;
            const int reg_c = regh_c + (wpc < 49 ? 0 : (wpc < 53 ? 1 : 2));
            const float* krow = krow0 + src_c * CH;
            const float bv = bias[biaslane + ((6 - ic) * 13 + (6 - u)) * 16];
            float s0 = fmaf(bv, LOG2E, (reg_r != reg_c) ? -167.26950408889634f : -23.0f);
            float s1 = 0.f, s2 = 0.f, s3 = 0.f;
#pragma unroll
            for (int d = 0; d < HD_; d += 4) {
                s0 = fmaf(qr[d+0], krow[d+0], s0);
                s1 = fmaf(qr[d+1], krow[d+1], s1);
                s2 = fmaf(qr[d+2], krow[d+2], s2);
                s3 = fmaf(qr[d+3], krow[d+3], s3);
            }
            e[u] = exp2f((s0 + s1) + (s2 + s3));
            denom += e[u];
        }
#pragma unroll
        for (int u = 0; u < WSZ; ++u) {
            const int wpc = wc * WSZ + u;
            int src_c = wpc + 3; if (src_c >= SP) src_c -= SP;
            const float* vrow = vrow0 + src_c * CH;
            const float ev = e[u];
#pragma unroll
            for (int d = 0; d < HD_; ++d) o[d] = fmaf(ev, vrow[d], o[d]);
        }
    }
    const float invd = 1.0f / denom;
    if (lane < NTOK) {
        float4* op = reinterpret_cast<float4*>(outg + rowoff);
#pragma unroll
        for (int tt = 0; tt < HD_ / 4; ++tt) {
            float4 x;
            x.x = o[4*tt+0] * invd; x.y = o[4*tt+1] * invd;
            x.z = o[4*tt+2] * invd; x.w = o[4*tt+3] * invd;
            op[tt] = x;
        }
    }
}

extern "C" void kernel_launch(void* const* d_in, const int* in_sizes, int n_in,
                              void* d_out, int out_size, void* d_ws, size_t ws_size,
                              hipStream_t stream) {
    const float* q    = (const float*)d_in[0];
    const float* k    = (const float*)d_in[1];
    const float* v    = (const float*)d_in[2];
    const float* bias = (const float*)d_in[3];
    float* out        = (float*)d_out;

    const int B   = in_sizes[0] / (SP * SP * CH);
    const int nwh = B * (SP / WSZ) * (SP / WSZ) * NH_;   // 16384

    const size_t bm_bytes = (size_t)NH_ * 4 * 4096 * sizeof(_Float16);  // 512 KB
    if (ws_size >= bm_bytes) {
        _Float16* bm = (_Float16*)d_ws;
        (void)hipFuncSetAttribute(
            reinterpret_cast<const void*>(swin_glds_kernel),
            hipFuncAttributeMaxDynamicSharedMemorySize, (int)LDS_BYTES);
        hipLaunchKernelGGL(build_bm, dim3(NH_ * 4), dim3(256), 0, stream, bias, bm);
        // 4 whs per wave, 4 waves per block -> nwh/16 blocks
        hipLaunchKernelGGL(swin_glds_kernel, dim3(nwh / 16), dim3(256), LDS_BYTES,
                           stream, q, k, v, bm, out);
    } else {
        hipLaunchKernelGGL(swin_block_scalar, dim3(nwh / 4), dim3(256), 0, stream,
                           q, k, v, bias, out);
    }
}

// Round 14
// 111.275 us; speedup vs baseline: 1.0345x; 1.0345x over previous
//
#include <hip/hip_runtime.h>
#include <stdint.h>

// Swin shifted-window attention, MI355X (gfx950) — round 14.
// r12 pipeline + O^T REFORMULATION of PV. Diagnosis: per-wh wall ~29k cy >>
// ~3.5k VALU-issue; the largest serial chunk is the store epilogue's 32
// dependent __shfl (16 shfl(inv) + 16 shfl(oo), ~120cy each) + 32 scalar
// stores. Fix is algebraic: swap PV operand order -> mfma(A=Vb, B=PA)
// computes C[d][q] = O^T (A/B frags share the same lane layout, so the
// EXISTING Vb and PA fragments are already correct). C-layout col=l16=q,
// row=4g+r=d: inv[tq] becomes lane-local, stores become 8 float4 at
// oQK[tq]+16dh+4g — ZERO epilogue shuffles. Everything else = r12.
// Observable: SQ_LDS_BANK_CONFLICT should drop ~25-30% (fewer bpermutes).

constexpr int WSZ  = 7;
constexpr int NTOK = 49;
constexpr int NH_  = 16;
constexpr int HD_  = 32;
constexpr int SP   = 56;
constexpr int CH   = 512;
constexpr float LOG2E = 1.4426950408889634f;

typedef float    f32x4 __attribute__((ext_vector_type(4)));
typedef short    s16x8 __attribute__((ext_vector_type(8)));
typedef _Float16 f16x4 __attribute__((ext_vector_type(4)));

union FragU { uint32_t w[4]; s16x8 v; };

__device__ __forceinline__ uint32_t bf16_hibits(float x) {
    uint32_t u = __float_as_uint(x);
    u += 0x7fffu + ((u >> 16) & 1u);
    return u & 0xffff0000u;
}
__device__ __forceinline__ uint32_t pk_bf16(float a, float b) {
    return (bf16_hibits(a) >> 16) | bf16_hibits(b);
}

// ---------------- pre-kernel: bias+mask matrices (f16) ----------------
// bm[h*4+cls][q][m] (64x64 f16) = (bias+mask)*LOG2E; padding = -1000.
__global__ __launch_bounds__(256)
void build_bm(const float* __restrict__ bias, _Float16* __restrict__ bm)
{
    const int blk = blockIdx.x;          // h*4 + cls
    const int h = blk >> 2, cls = blk & 3;
    for (int idx = threadIdx.x; idx < 4096; idx += 256) {
        const int q = idx >> 6, m = idx & 63;
        float val;
        if (q >= NTOK || m >= NTOK) {
            val = -1000.0f;
        } else {
            const int iq = q / 7, jq = q % 7, im = m / 7, jm = m % 7;
            const int rpi = (iq - im + 6) * 13 + (jq - jm + 6);
            const float bv = bias[rpi * NH_ + h];
            const int rq = ((cls & 2) ? (iq < 4 ? 3 : 6) : 0)
                         + ((cls & 1) ? (jq < 4 ? 1 : 2) : 0);
            const int rm = ((cls & 2) ? (im < 4 ? 3 : 6) : 0)
                         + ((cls & 1) ? (jm < 4 ? 1 : 2) : 0);
            const float mask = (rq != rm) ? -100.0f : 0.0f;
            val = (bv + mask) * LOG2E;
        }
        bm[blk * 4096 + idx] = (_Float16)val;
    }
}

// ---------------- pipeline building blocks ----------------
struct Raw {
    float4 q[4][2];
    float4 k[4][2];
    float  v[2][2][8];
};
struct Frag {
    s16x8 Qh[4], Kh[4], Vb[2][2];
};

__device__ __forceinline__ int make_off(int wh, int lane) {
    const int h  = wh & 15;
    const int w  = wh >> 4;
    const int wc = w & 7, wr = (w >> 3) & 7, b = w >> 6;
    const int t  = lane < NTOK ? lane : NTOK - 1;
    const int it = t / 7, jt = t - 7 * it;
    int sr = wr * 7 + it + 3; if (sr >= SP) sr -= SP;
    int sc = wc * 7 + jt + 3; if (sc >= SP) sc -= SP;
    return ((b * SP + sr) * SP + sc) * CH + h * HD_;
}
__device__ __forceinline__ int cls_of(int wh) {
    const int w = wh >> 4;
    return ((((w >> 3) & 7) == 7) ? 2 : 0) | (((w & 7) == 7) ? 1 : 0);
}

// loads; also returns oQK (per-lane offset of token 16tt+l16) for the stores
__device__ __forceinline__ void issue_qkv(const float* __restrict__ qg,
                                          const float* __restrict__ kg,
                                          const float* __restrict__ vg,
                                          int off, int l16, int g, Raw& r,
                                          int (&oQK)[4]) {
#pragma unroll
    for (int tt = 0; tt < 4; ++tt) oQK[tt] = __shfl(off, 16 * tt + l16);
    int oV[16];
#pragma unroll
    for (int mc = 0; mc < 2; ++mc)
#pragma unroll
        for (int e = 0; e < 8; ++e) oV[8 * mc + e] = __shfl(off, 32 * mc + 8 * g + e);
#pragma unroll
    for (int tt = 0; tt < 4; ++tt) {
        const float* qp = qg + oQK[tt] + 8 * g;
        const float* kp = kg + oQK[tt] + 8 * g;
        r.q[tt][0] = *(const float4*)qp;  r.q[tt][1] = *(const float4*)(qp + 4);
        r.k[tt][0] = *(const float4*)kp;  r.k[tt][1] = *(const float4*)(kp + 4);
    }
#pragma unroll
    for (int mc = 0; mc < 2; ++mc)
#pragma unroll
        for (int dh = 0; dh < 2; ++dh)
#pragma unroll
            for (int e = 0; e < 8; ++e)
                r.v[mc][dh][e] = vg[oV[8 * mc + e] + 16 * dh + l16];
}

__device__ __forceinline__ void convertQKV(const Raw& r, float qs, Frag& f) {
#pragma unroll
    for (int tt = 0; tt < 4; ++tt) {
        FragU qh, kh;
        qh.w[0] = pk_bf16(r.q[tt][0].x * qs, r.q[tt][0].y * qs);
        qh.w[1] = pk_bf16(r.q[tt][0].z * qs, r.q[tt][0].w * qs);
        qh.w[2] = pk_bf16(r.q[tt][1].x * qs, r.q[tt][1].y * qs);
        qh.w[3] = pk_bf16(r.q[tt][1].z * qs, r.q[tt][1].w * qs);
        kh.w[0] = pk_bf16(r.k[tt][0].x, r.k[tt][0].y);
        kh.w[1] = pk_bf16(r.k[tt][0].z, r.k[tt][0].w);
        kh.w[2] = pk_bf16(r.k[tt][1].x, r.k[tt][1].y);
        kh.w[3] = pk_bf16(r.k[tt][1].z, r.k[tt][1].w);
        f.Qh[tt] = qh.v; f.Kh[tt] = kh.v;
    }
#pragma unroll
    for (int mc = 0; mc < 2; ++mc)
#pragma unroll
        for (int dh = 0; dh < 2; ++dh) {
            FragU fu;
#pragma unroll
            for (int wd = 0; wd < 4; ++wd)
                fu.w[wd] = pk_bf16(r.v[mc][dh][2 * wd], r.v[mc][dh][2 * wd + 1]);
            f.Vb[mc][dh] = fu.v;
        }
}

__device__ __forceinline__ void load_bm(const _Float16* __restrict__ bmh,
                                        int l16, int g, f16x4 (&bmr)[4][4]) {
#pragma unroll
    for (int tq = 0; tq < 4; ++tq)
#pragma unroll
        for (int tk = 0; tk < 4; ++tk)
            bmr[tq][tk] = *(const f16x4*)(bmh + (16 * tq + l16) * 64 + 16 * tk + 4 * g);
}

__device__ __forceinline__ void do_math(const Frag& f, const f16x4 (&bmr)[4][4],
                                        const int (&oQK)[4], int lane, int g, int l16,
                                        float* __restrict__ outg) {
    // S^T = K·Q^T tiles, fused exp2 + bf16 pack + denom
    uint32_t u0[4][4], u1[4][4];
    float inv[4];
#pragma unroll
    for (int tq = 0; tq < 4; ++tq) {
        float dsum = 0.f;
#pragma unroll
        for (int tk = 0; tk < 4; ++tk) {
            f32x4 a;
            a[0] = (float)bmr[tq][tk][0] - 23.f;
            a[1] = (float)bmr[tq][tk][1] - 23.f;
            a[2] = (float)bmr[tq][tk][2] - 23.f;
            a[3] = (float)bmr[tq][tk][3] - 23.f;
            a = __builtin_amdgcn_mfma_f32_16x16x32_bf16(f.Kh[tk], f.Qh[tq], a, 0, 0, 0);
            float e0 = __builtin_amdgcn_exp2f(a[0]);
            float e1 = __builtin_amdgcn_exp2f(a[1]);
            float e2 = __builtin_amdgcn_exp2f(a[2]);
            float e3 = __builtin_amdgcn_exp2f(a[3]);
            dsum += (e0 + e1) + (e2 + e3);
            u0[tq][tk] = pk_bf16(e0, e1);
            u1[tq][tk] = pk_bf16(e2, e3);
        }
        dsum += __shfl_xor(dsum, 16);
        dsum += __shfl_xor(dsum, 32);
        inv[tq] = 1.0f / (dsum + 1e-30f);   // lane-local for q = 16tq + l16
    }

    // repack P (C-layout) -> fragments (r10-validated; serves as B-operand:
    // B[k=m][col=q] has the SAME lane layout as the old A-operand)
    const int srcb = 32 * (g & 1) + l16;
    const bool hiG = (lane >= 32);
    s16x8 PA[4][2];
#pragma unroll
    for (int tq = 0; tq < 4; ++tq)
#pragma unroll
        for (int mc = 0; mc < 2; ++mc) {
            FragU fu;
#pragma unroll
            for (int wd = 0; wd < 4; ++wd) {
                const int sl = srcb + 16 * (wd >> 1);
                uint32_t A, B;
                if (wd & 1) {
                    A = __shfl(u1[tq][2 * mc],     sl);
                    B = __shfl(u1[tq][2 * mc + 1], sl);
                } else {
                    A = __shfl(u0[tq][2 * mc],     sl);
                    B = __shfl(u0[tq][2 * mc + 1], sl);
                }
                fu.w[wd] = hiG ? B : A;
            }
            PA[tq][mc] = fu.v;
        }

    // O^T = V^T·P^T: mfma(A=Vb, B=PA) -> C[d][q].
    // C-layout: col = l16 = q (within tile tq), row = 4g+r = d (within 16dh).
    // Store: lane-local float4 at oQK[tq] + 16dh + 4g; iv = inv[tq] (no shfl).
#pragma unroll
    for (int tq = 0; tq < 4; ++tq) {
        const float iv = inv[tq];
        const bool ok = (tq < 3) || (l16 == 0);     // token 16tq+l16 < 49
#pragma unroll
        for (int dh = 0; dh < 2; ++dh) {
            f32x4 a = {0.f, 0.f, 0.f, 0.f};
            a = __builtin_amdgcn_mfma_f32_16x16x32_bf16(f.Vb[0][dh], PA[tq][0], a, 0, 0, 0);
            a = __builtin_amdgcn_mfma_f32_16x16x32_bf16(f.Vb[1][dh], PA[tq][1], a, 0, 0, 0);
            if (ok) {
                float4 st;
                st.x = a[0] * iv; st.y = a[1] * iv;
                st.z = a[2] * iv; st.w = a[3] * iv;
                *(float4*)(outg + oQK[tq] + 16 * dh + 4 * g) = st;
            }
        }
    }
}

// ---------------- main pipelined kernel ----------------
__global__ __launch_bounds__(256, 2)
void swin_pipe_kernel(const float* __restrict__ qg,
                      const float* __restrict__ kg,
                      const float* __restrict__ vg,
                      const _Float16* __restrict__ bm,
                      float* __restrict__ outg)
{
    const int wave = threadIdx.x >> 6;
    const int gw   = blockIdx.x * 4 + wave;     // 0..4095; wh_i = gw + 4096*i
    const int lane = threadIdx.x & 63;
    const int g    = lane >> 4;
    const int l16  = lane & 15;
    const float qs = 0.17677669529663687f * LOG2E;   // (1/sqrt(32))*log2(e)

    const int h = gw & 15;                            // head constant over i
    const _Float16* bmhead = bm + (size_t)h * 4 * 4096;

    Raw A, B;
    Frag f;
    f16x4 bmr[4][4];
    int oA[4], oB[4];

    const int wh0 = gw;
    const int off0 = make_off(wh0, lane);
    issue_qkv(qg, kg, vg, off0, l16, g, A, oA);

    // ---- iteration 0 (compute A, prefetch B=wh1) ----
    convertQKV(A, qs, f);
    load_bm(bmhead + cls_of(wh0) * 4096, l16, g, bmr);
    const int wh1 = gw + 4096;
    const int off1 = make_off(wh1, lane);
    issue_qkv(qg, kg, vg, off1, l16, g, B, oB);
    __builtin_amdgcn_sched_barrier(0);
    do_math(f, bmr, oA, lane, g, l16, outg);

    // ---- iteration 1 (compute B, prefetch A=wh2) ----
    convertQKV(B, qs, f);
    load_bm(bmhead + cls_of(wh1) * 4096, l16, g, bmr);
    const int wh2 = gw + 8192;
    const int off2 = make_off(wh2, lane);
    issue_qkv(qg, kg, vg, off2, l16, g, A, oA);
    __builtin_amdgcn_sched_barrier(0);
    do_math(f, bmr, oB, lane, g, l16, outg);

    // ---- iteration 2 (compute A, prefetch B=wh3) ----
    convertQKV(A, qs, f);
    load_bm(bmhead + cls_of(wh2) * 4096, l16, g, bmr);
    const int wh3 = gw + 12288;
    const int off3 = make_off(wh3, lane);
    issue_qkv(qg, kg, vg, off3, l16, g, B, oB);
    __builtin_amdgcn_sched_barrier(0);
    do_math(f, bmr, oA, lane, g, l16, outg);

    // ---- iteration 3 (compute B, no prefetch) ----
    convertQKV(B, qs, f);
    load_bm(bmhead + cls_of(wh3) * 4096, l16, g, bmr);
    __builtin_amdgcn_sched_barrier(0);
    do_math(f, bmr, oB, lane, g, l16, outg);
}

// ---------------- fallback scalar kernel (round-3) ----------------
__global__ __launch_bounds__(256)
void swin_block_scalar(const float* __restrict__ qg,
                       const float* __restrict__ kg,
                       const float* __restrict__ vg,
                       const float* __restrict__ bias,
                       float* __restrict__ outg)
{
    const int wave = __builtin_amdgcn_readfirstlane(threadIdx.x >> 6);
    const int wh   = blockIdx.x * 4 + wave;
    const int h    = wh & (NH_ - 1);
    const int w    = wh >> 4;
    const int wc   = w & 7;
    const int wr   = (w >> 3) & 7;
    const int b    = w >> 6;

    const int lane = threadIdx.x & 63;
    const int rr   = lane < NTOK ? lane : NTOK - 1;
    const int i    = rr / WSZ;
    const int j    = rr - i * WSZ;

    const int hp = wr * WSZ + i;
    const int wp = wc * WSZ + j;
    int sr = hp + 3; if (sr >= SP) sr -= SP;
    int sc = wp + 3; if (sc >= SP) sc -= SP;
    const int rowoff = ((b * SP + sr) * SP + sc) * CH + h * HD_;
    const int reg_r = (hp < 49 ? 0 : (hp < 53 ? 3 : 6))
                    + (wp < 49 ? 0 : (wp < 53 ? 1 : 2));
    const float qscale = 0.17677669529663687f * LOG2E;

    float qr[HD_];
    {
        const float4* qp = reinterpret_cast<const float4*>(qg + rowoff);
#pragma unroll
        for (int tt = 0; tt < HD_ / 4; ++tt) {
            float4 x = qp[tt];
            qr[4*tt+0] = x.x * qscale; qr[4*tt+1] = x.y * qscale;
            qr[4*tt+2] = x.z * qscale; qr[4*tt+3] = x.w * qscale;
        }
    }
    const int biaslane = (i * 13 + j) * 16 + h;
    float o[HD_];
#pragma unroll
    for (int d = 0; d < HD_; ++d) o[d] = 0.f;
    float denom = 0.f;
    const float* kb = kg + b * SP * SP * CH + h * HD_;
    const float* vb = vg + b * SP * SP * CH + h * HD_;

    for (int ic = 0; ic < WSZ; ++ic) {
        const int hpc = wr * WSZ + ic;
        int src_r = hpc + 3; if (src_r >= SP) src_r -= SP;
        const int regh_c = (hpc < 49 ? 0 : (hpc < 53 ? 3 : 6));
        const float* krow0 = kb + src_r * SP * CH;
        const float* vrow0 = vb + src_r * SP * CH;
        float e[WSZ];
#pragma unroll
        for (int u = 0; u < WSZ; ++u) {
            const int wpc = wc * WSZ + u;
            int src_c = wpc + 3; if (src_c >= SP) src_c -= SP;
            const int reg_c = regh_c + (wpc < 49 ? 0 : (wpc < 53 ? 1 : 2));
            const float* krow = krow0 + src_c * CH;
            const float bv = bias[biaslane + ((6 - ic) * 13 + (6 - u)) * 16];
            float s0 = fmaf(bv, LOG2E, (reg_r != reg_c) ? -167.26950408889634f : -23.0f);
            float s1 = 0.f, s2 = 0.f, s3 = 0.f;
#pragma unroll
            for (int d = 0; d < HD_; d += 4) {
                s0 = fmaf(qr[d+0], krow[d+0], s0);
                s1 = fmaf(qr[d+1], krow[d+1], s1);
                s2 = fmaf(qr[d+2], krow[d+2], s2);
                s3 = fmaf(qr[d+3], krow[d+3], s3);
            }
            e[u] = exp2f((s0 + s1) + (s2 + s3));
            denom += e[u];
        }
#pragma unroll
        for (int u = 0; u < WSZ; ++u) {
            const int wpc = wc * WSZ + u;
            int src_c = wpc + 3; if (src_c >= SP) src_c -= SP;
            const float* vrow = vrow0 + src_c * CH;
            const float ev = e[u];
#pragma unroll
            for (int d = 0; d < HD_; ++d) o[d] = fmaf(ev, vrow[d], o[d]);
        }
    }
    const float invd = 1.0f / denom;
    if (lane < NTOK) {
        float4* op = reinterpret_cast<float4*>(outg + rowoff);
#pragma unroll
        for (int tt = 0; tt < HD_ / 4; ++tt) {
            float4 x;
            x.x = o[4*tt+0] * invd; x.y = o[4*tt+1] * invd;
            x.z = o[4*tt+2] * invd; x.w = o[4*tt+3] * invd;
            op[tt] = x;
        }
    }
}

extern "C" void kernel_launch(void* const* d_in, const int* in_sizes, int n_in,
                              void* d_out, int out_size, void* d_ws, size_t ws_size,
                              hipStream_t stream) {
    const float* q    = (const float*)d_in[0];
    const float* k    = (const float*)d_in[1];
    const float* v    = (const float*)d_in[2];
    const float* bias = (const float*)d_in[3];
    float* out        = (float*)d_out;

    const int B   = in_sizes[0] / (SP * SP * CH);
    const int nwh = B * (SP / WSZ) * (SP / WSZ) * NH_;   // 16384

    const size_t bm_bytes = (size_t)NH_ * 4 * 4096 * sizeof(_Float16);  // 512 KB
    if (ws_size >= bm_bytes) {
        _Float16* bm = (_Float16*)d_ws;
        hipLaunchKernelGGL(build_bm, dim3(NH_ * 4), dim3(256), 0, stream, bias, bm);
        // 4 whs per wave, 4 waves per block -> nwh/16 blocks
        hipLaunchKernelGGL(swin_pipe_kernel, dim3(nwh / 16), dim3(256), 0, stream,
                           q, k, v, bm, out);
    } else {
        hipLaunchKernelGGL(swin_block_scalar, dim3(nwh / 4), dim3(256), 0, stream,
                           q, k, v, bias, out);
    }
}